// Round 10
// baseline (7138.234 us; speedup 1.0000x reference)
//
#include <hip/hip_runtime.h>

// Problem constants (match reference)
#define NN   200000   // nodes
#define NE   400000   // edges (without self loops)
#define NG   4096     // graphs
#define EMB  300
#define SD   304      // storage stride in bf16 elems (16B-aligned; 38 slots of 8)
#define SLOTS 38      // 16B slots per stored row
#define NROW 200064   // padded rows (for buffer sizing only)
#define FEAT 256
#define LAYERS 5
#define NREP 16       // stats atomic replicas

typedef __attribute__((ext_vector_type(8))) short short8;   // 8 x bf16 (4 VGPR)
typedef __attribute__((ext_vector_type(4))) float f32x4;

__device__ __forceinline__ float bf2f(unsigned short u){
  union { unsigned int i; float f; } v; v.i = ((unsigned int)u) << 16; return v.f;
}
__device__ __forceinline__ unsigned short f2bf(float f){
  union { float f; unsigned int i; } v; v.f = f;
  return (unsigned short)((v.i + 0x7fffu + ((v.i >> 16) & 1u)) >> 16);
}

// ---------------------------------------------------------------- Wt build
// Wt[l][j][k] = bf16(W[l][k][j]), padded to [320][304] per layer (zeros outside 300x300)
__global__ void k_wt(const float* __restrict__ W, unsigned short* __restrict__ Wt){
  int idx = blockIdx.x * 256 + threadIdx.x;            // 5*320*304 = 486400 items
  if (idx >= LAYERS * 320 * SD) return;
  int l = idx / (320 * SD);
  int rem = idx - l * 320 * SD;
  int j = rem / SD, k = rem - (rem / SD) * SD;
  unsigned short v = 0;
  if (j < EMB && k < EMB) v = f2bf(W[l * EMB * EMB + k * EMB + j]);
  Wt[idx] = v;
}

// ---------------------------------------------------------------- embedding
__global__ __launch_bounds__(256) void k_embed(const int* __restrict__ x,
    const float* __restrict__ emb1, const float* __restrict__ emb2,
    unsigned short* __restrict__ H){
  __shared__ float e1s[900], e2s[900];                 // x values are in [0,3)
  int tid = threadIdx.x;
  for (int k = tid; k < 900; k += 256){ e1s[k] = emb1[k]; e2s[k] = emb2[k]; }
  __syncthreads();
  int t = blockIdx.x * 256 + tid;                      // one 16B slot per thread
  int i = t / SLOTS, c = t - (t / SLOTS) * SLOTS;
  if (i >= NN) return;
  int x0 = x[2 * i], x1 = x[2 * i + 1];
  int cb = c * 8;
  unsigned short o[8];
#pragma unroll
  for (int e = 0; e < 8; ++e){
    int col = cb + e; float v = 0.f;
    if (col < EMB) v = e1s[x0 * EMB + col] + e2s[x1 * EMB + col];
    o[e] = f2bf(v);
  }
  *reinterpret_cast<uint4*>(H + (size_t)i * SD + cb) = *reinterpret_cast<uint4*>(o);
}

// ---------------------------------------------------------------- CSR build
__global__ void k_deg(const int* __restrict__ ei, int* __restrict__ deg){
  int e = blockIdx.x * 256 + threadIdx.x;
  if (e < NE) atomicAdd(&deg[ei[NE + e]], 1);
}
__global__ void k_scan1(const int* __restrict__ deg, int* __restrict__ incl, int* __restrict__ bsum){
  __shared__ int sm[256];
  int t = threadIdx.x; int i = blockIdx.x * 256 + t;
  int v = (i < NN) ? deg[i] : 0; sm[t] = v;
  for (int o = 1; o < 256; o <<= 1){
    __syncthreads(); int xx = (t >= o) ? sm[t - o] : 0;
    __syncthreads(); sm[t] += xx;
  }
  __syncthreads();
  if (i < NN) incl[i] = sm[t];
  if (t == 255) bsum[blockIdx.x] = sm[255];
}
__global__ void k_scan2(const int* __restrict__ bsum, int* __restrict__ bincl){
  __shared__ int sm[1024];
  int t = threadIdx.x;
  int v = (t < 782) ? bsum[t] : 0; sm[t] = v;
  for (int o = 1; o < 1024; o <<= 1){
    __syncthreads(); int xx = (t >= o) ? sm[t - o] : 0;
    __syncthreads(); sm[t] += xx;
  }
  __syncthreads();
  bincl[t] = sm[t];
}
__global__ void k_scan3(const int* __restrict__ incl, const int* __restrict__ deg,
    const int* __restrict__ bincl, int* __restrict__ rowPtr){
  int i = blockIdx.x * 256 + threadIdx.x;
  if (i < NN) rowPtr[i] = incl[i] - deg[i] + (blockIdx.x ? bincl[blockIdx.x - 1] : 0);
}
__global__ void k_fill(const int* __restrict__ ei, const int* __restrict__ ea,
    const int* __restrict__ rowPtr, int* __restrict__ cursor, int* __restrict__ csr){
  int e = blockIdx.x * 256 + threadIdx.x;
  if (e >= NE) return;
  int dst = ei[NE + e], src = ei[e];
  int code = ea[2 * e] * 3 + ea[2 * e + 1];      // ea0,ea1 in 0..2
  int pos = atomicAdd(&cursor[dst], 1);
  csr[rowPtr[dst] + pos] = src | (code << 20);   // src fits 18 bits
}

// ---------------------------------------------------------------- FUSED layer
// Gather-accumulate f(H[src]) into MFMA A-fragment registers with a two-half
// software pipeline (load next half || accumulate previous half), then MFMA,
// bias + edge scalar + BN stats, write H_next. No intermediate buffer.
// A-frag mapping: row = wave*16+(lane&15); kg = lane>>4; k = m*32+kg*8+e.
__global__ __launch_bounds__(256, 3) void k_fused(
    const unsigned short* __restrict__ Hin, const unsigned short* __restrict__ Wt,
    const float2* __restrict__ st, const int* __restrict__ rowPtr,
    const int* __restrict__ deg, const int* __restrict__ csr,
    const float* __restrict__ e1l, const float* __restrict__ e2l,
    const float* __restrict__ bl, unsigned short* __restrict__ Hout,
    float* __restrict__ cs, int relu){
  __shared__ unsigned short bLds[64 * 320];   // 40KB B tile; reused as out tile
  __shared__ float2 stl[SD];
  __shared__ float eetab[9];
  __shared__ float eeself_s;
  __shared__ float cvl[64];
  int tid = threadIdx.x, lane = tid & 63, wave = tid >> 6;
  for (int j = tid; j < SD; j += 256) stl[j] = st[j];
  if (tid < 9) eetab[tid] = e1l[tid / 3] + e2l[tid % 3];
  if (tid == 9) eeself_s = e1l[4] + e2l[0];
  __syncthreads();
  int r0 = blockIdx.x * 64;                    // grid = NN/64 = 3125 exactly
  int rloc = wave * 16 + (lane & 15);          // local dst row 0..63
  int row = r0 + rloc;
  int kg = lane >> 4;                          // 0..3

  // ---- gather-accumulate (f32, A-frag layout), half-row pipelined
  float accv[10][8];
#pragma unroll
  for (int m = 0; m < 10; ++m)
#pragma unroll
    for (int e = 0; e < 8; ++e) accv[m][e] = 0.f;

  uint4 h0[5], h1[5];
  auto loadH0 = [&](int src){
    const unsigned short* p = Hin + (size_t)src * SD + kg * 8;
#pragma unroll
    for (int m = 0; m < 5; ++m)
      h0[m] = *reinterpret_cast<const uint4*>(p + m * 32);
  };
  auto loadH1 = [&](int src){
    const unsigned short* p = Hin + (size_t)src * SD + kg * 8 + 160;
#pragma unroll
    for (int m = 0; m < 5; ++m)
      if (m < 4 || kg < 2)                     // k<304 only (gm=9, kg>=2 is pad)
        h1[m] = *reinterpret_cast<const uint4*>(p + m * 32);
  };
  auto accH0 = [&](){
#pragma unroll
    for (int m = 0; m < 5; ++m){
      unsigned int w[4] = {h0[m].x, h0[m].y, h0[m].z, h0[m].w};
      int cb = m * 32 + kg * 8;
#pragma unroll
      for (int e = 0; e < 8; ++e){
        unsigned short u = (e & 1) ? (unsigned short)(w[e >> 1] >> 16)
                                   : (unsigned short)(w[e >> 1] & 0xffff);
        float2 sv = stl[cb + e];
        float xv = sv.x * bf2f(u) + sv.y;
        if (relu) xv = fmaxf(xv, 0.f);
        accv[m][e] += xv;
      }
    }
  };
  auto accH1 = [&](){
#pragma unroll
    for (int m = 0; m < 5; ++m){
      if (m < 4 || kg < 2){
        unsigned int w[4] = {h1[m].x, h1[m].y, h1[m].z, h1[m].w};
        int cb = (m + 5) * 32 + kg * 8;
#pragma unroll
        for (int e = 0; e < 8; ++e){
          unsigned short u = (e & 1) ? (unsigned short)(w[e >> 1] >> 16)
                                     : (unsigned short)(w[e >> 1] & 0xffff);
          float2 sv = stl[cb + e];
          float xv = sv.x * bf2f(u) + sv.y;
          if (relu) xv = fmaxf(xv, 0.f);
          accv[m + 5][e] += xv;
        }
      }
    }
  };

  float csum = eeself_s;
  int st0 = rowPtr[row], cnt = deg[row];
  loadH0(row); loadH1(row);                    // self row in flight
  if (cnt > 0){
    int pc = csr[st0];
    for (int e = 0; e < cnt; ++e){
      int pn = (e + 1 < cnt) ? csr[st0 + e + 1] : 0;   // prefetch next csr entry
      csum += eetab[pc >> 20];
      int src = pc & 0xFFFFF;
      accH0();                                  // consume prev row's H0
      loadH0(src);                              // issue this edge's H0
      accH1();                                  // consume prev row's H1
      loadH1(src);                              // issue this edge's H1
      pc = pn;
    }
  }
  accH0(); accH1();                             // consume last row
  if (kg == 0) cvl[rloc] = csum;

  // ---- convert to bf16 A-fragments
  short8 afr[10];
#pragma unroll
  for (int m = 0; m < 10; ++m){
    unsigned short o[8];
#pragma unroll
    for (int e = 0; e < 8; ++e) o[e] = f2bf(accv[m][e]);
    afr[m] = *reinterpret_cast<short8*>(o);
  }

  // ---- MFMA phase
  f32x4 acc[20];
#pragma unroll
  for (int a = 0; a < 20; ++a) acc[a] = (f32x4){0.f, 0.f, 0.f, 0.f};
#pragma unroll
  for (int jt = 0; jt < 5; ++jt){
    __syncthreads();
#pragma unroll
    for (int it = 0; it < 10; ++it){
      int s = it * 256 + tid;
      int jl = s / 40, cc = s - (s / 40) * 40;
      int srcC = cc ^ (jl & 7);
      uint4 v = make_uint4(0u, 0u, 0u, 0u);
      if (srcC < SLOTS)
        v = *reinterpret_cast<const uint4*>(Wt + ((size_t)(jt * 64 + jl) * SD + srcC * 8));
      *reinterpret_cast<uint4*>(&bLds[jl * 320 + cc * 8]) = v;
    }
    __syncthreads();
#pragma unroll
    for (int kc = 0; kc < 10; ++kc){
#pragma unroll
      for (int fl = 0; fl < 4; ++fl){
        int jl = fl * 16 + (lane & 15);
        int cw = kc * 4 + (lane >> 4);
        int cs_ = cw ^ (jl & 7);
        short8 bfr = *reinterpret_cast<const short8*>(&bLds[jl * 320 + cs_ * 8]);
        acc[jt * 4 + fl] = __builtin_amdgcn_mfma_f32_16x16x32_bf16(afr[kc], bfr, acc[jt * 4 + fl], 0, 0, 0);
      }
    }
  }
  __syncthreads();
  // ---- epilogue: + cvl + bias, stage bf16 tile into LDS (reuse bLds)
  unsigned short* oLds = bLds;
  {
    int rb = wave * 16 + (lane >> 4) * 4;
#pragma unroll
    for (int r = 0; r < 4; ++r){
      int lrow = rb + r;
      float cv = cvl[lrow];
#pragma unroll
      for (int a = 0; a < 20; ++a){
        int col = (a >> 2) * 64 + (a & 3) * 16 + (lane & 15);
        if (col < SD){
          float bv = (col < EMB) ? bl[col] : 0.f;
          oLds[lrow * SD + col] = f2bf(acc[a][r] + cv + bv);
        }
      }
    }
  }
  __syncthreads();
  // ---- fused BN stats: column sum/sumsq over 64 rows (NREP atomic replicas)
  {
    float* csr_ = cs + (size_t)(blockIdx.x & (NREP - 1)) * 2 * SD;
    for (int c = tid; c < EMB; c += 256){
      float s = 0.f, s2 = 0.f;
#pragma unroll 4
      for (int r = 0; r < 64; ++r){
        float v = bf2f(oLds[r * SD + c]);
        s += v; s2 += v * v;
      }
      atomicAdd(&csr_[c], s); atomicAdd(&csr_[SD + c], s2);
    }
  }
  // ---- coalesced contiguous tile write (2432 consecutive 16B slots)
  for (int s = tid; s < 64 * SLOTS; s += 256){
    *reinterpret_cast<uint4*>(Hout + (size_t)r0 * SD + s * 8) =
        *reinterpret_cast<const uint4*>(&bLds[(s / SLOTS) * SD + (s - (s / SLOTS) * SLOTS) * 8]);
  }
}

// ---------------------------------------------------------------- BN finalize
__global__ void k_stfin(const float* __restrict__ cs, const float* __restrict__ gam,
    const float* __restrict__ bet, float2* __restrict__ st){
  int j = threadIdx.x;            // SD threads
  if (j < EMB){
    float sm = 0.f, sq = 0.f;
    for (int r = 0; r < NREP; ++r){
      sm += cs[(size_t)r * 2 * SD + j];
      sq += cs[(size_t)r * 2 * SD + SD + j];
    }
    float mean = sm * (1.f / NN);
    float var = sq * (1.f / NN) - mean * mean;
    float rr = rsqrtf(var + 1e-5f);
    float s = gam[j] * rr;
    st[j] = make_float2(s, bet[j] - mean * s);
  } else if (j < SD) st[j] = make_float2(0.f, 0.f);
}
__global__ void k_stinit(float2* __restrict__ st){
  int j = threadIdx.x; if (j < SD) st[j] = make_float2(1.f, 0.f);
}

// ---------------------------------------------------------------- pool + heads
__global__ void k_pool(const unsigned short* __restrict__ H, const float2* __restrict__ st,
    const int* __restrict__ batch, float* __restrict__ hg){
  int gph = blockIdx.x, j = threadIdx.x;     // 320 threads
  if (j >= SD) return;
  int lo, hi;
  { int a = 0, bn = NN; while (a < bn){ int m = (a + bn) >> 1; if (batch[m] < gph) a = m + 1; else bn = m; } lo = a; }
  { int a = lo, bn = NN; while (a < bn){ int m = (a + bn) >> 1; if (batch[m] < gph + 1) a = m + 1; else bn = m; } hi = a; }
  float acc = 0.f;
  for (int i = lo; i < hi; ++i) acc += bf2f(H[(size_t)i * SD + j]);
  int cnt = hi - lo;
  float2 sv = st[j];
  hg[gph * SD + j] = (sv.x * acc + (float)cnt * sv.y) / (float)max(cnt, 1);
}
__global__ __launch_bounds__(256) void k_head1(const float* __restrict__ hg,
    const float* __restrict__ fW, const float* __restrict__ fb,
    float* __restrict__ out0){
  __shared__ float row[EMB];
  int g = blockIdx.x, t = threadIdx.x;
  for (int j = t; j < EMB; j += 256) row[j] = hg[g * SD + j];
  __syncthreads();
  float acc = fb[t];
  for (int j = 0; j < EMB; ++j) acc += row[j] * fW[j * FEAT + t];
  out0[g * FEAT + t] = acc;
}
__global__ __launch_bounds__(256) void k_head2(const float* __restrict__ hf,
    const float* __restrict__ W1, const float* __restrict__ b1,
    const float* __restrict__ W2, const float* __restrict__ b2,
    float* __restrict__ out1){
  __shared__ float row[FEAT];
  __shared__ float t1[FEAT];
  int g = blockIdx.x, t = threadIdx.x;
  row[t] = hf[g * FEAT + t];
  __syncthreads();
  float acc = b1[t];
  for (int k = 0; k < FEAT; ++k) acc += row[k] * W1[k * FEAT + t];
  t1[t] = fmaxf(acc, 0.f);
  __syncthreads();
  if (t < 128){
    float a2 = b2[t];
    for (int k = 0; k < FEAT; ++k) a2 += t1[k] * W2[k * 128 + t];
    out1[g * 128 + t] = a2;
  }
}

// ---------------------------------------------------------------- launcher
extern "C" void kernel_launch(void* const* d_in, const int* in_sizes, int n_in,
                              void* d_out, int out_size, void* d_ws, size_t ws_size,
                              hipStream_t stream){
  const int* x   = (const int*)d_in[0];
  const int* ei  = (const int*)d_in[1];
  const int* ea  = (const int*)d_in[2];
  const int* bat = (const int*)d_in[3];
  const float* emb1 = (const float*)d_in[4];
  const float* emb2 = (const float*)d_in[5];
  const float* W    = (const float*)d_in[6];
  const float* bb   = (const float*)d_in[7];
  const float* e1   = (const float*)d_in[8];
  const float* e2   = (const float*)d_in[9];
  const float* gam  = (const float*)d_in[10];
  const float* bet  = (const float*)d_in[11];
  const float* fW   = (const float*)d_in[12];
  const float* fb   = (const float*)d_in[13];
  const float* oW1  = (const float*)d_in[14];
  const float* ob1  = (const float*)d_in[15];
  const float* oW2  = (const float*)d_in[16];
  const float* ob2  = (const float*)d_in[17];
  float* out = (float*)d_out;

  // carve workspace (~248 MB total)
  unsigned char* ws = (unsigned char*)d_ws;
  size_t off = 0;
  auto carve = [&](size_t bytes) -> void* {
    off = (off + 255) & ~(size_t)255;
    void* p = ws + off; off += bytes; return p;
  };
  const size_t SZ_H = (size_t)NROW * SD * 2;                       // 121,638,912 B
  unsigned short* bufA = (unsigned short*)carve(SZ_H);
  unsigned short* bufB = (unsigned short*)carve(SZ_H);
  unsigned short* Wt = (unsigned short*)carve((size_t)LAYERS * 320 * SD * 2);
  int* deg     = (int*)carve((size_t)NN * 4);
  int* rowPtr  = (int*)carve((size_t)NN * 4);
  int* csr     = (int*)carve((size_t)NE * 4);
  int* bsum    = (int*)carve(1024 * 4);
  int* bincl   = (int*)carve(1024 * 4);
  float* colst = (float*)carve((size_t)NREP * 2 * SD * 4);
  float2* st   = (float2*)carve(SD * 8);
  size_t needed = off;
  if (ws_size < needed) return;   // diagnostic: finite absmax-fail => ws too small

  // dead-time aliases:
  //   incl/cursor live only during CSR build (before bufB's first write, layer 0);
  //   hg lives only after bufA's last read (layer-4 k_fused reads bufA, writes bufB).
  int* incl    = (int*)bufB;
  int* cursor  = (int*)((unsigned char*)bufB + (size_t)NN * 4);
  float* hg    = (float*)bufA;

  hipMemsetAsync(deg, 0, (size_t)NN * 4, stream);
  hipMemsetAsync(cursor, 0, (size_t)NN * 4, stream);

  k_wt<<<(LAYERS * 320 * SD + 255) / 256, 256, 0, stream>>>(W, Wt);
  k_embed<<<(NN * SLOTS + 255) / 256, 256, 0, stream>>>(x, emb1, emb2, bufA);
  k_stinit<<<1, SD, 0, stream>>>(st);
  k_deg<<<(NE + 255) / 256, 256, 0, stream>>>(ei, deg);
  k_scan1<<<782, 256, 0, stream>>>(deg, incl, bsum);
  k_scan2<<<1, 1024, 0, stream>>>(bsum, bincl);
  k_scan3<<<782, 256, 0, stream>>>(incl, deg, bincl, rowPtr);
  k_fill<<<(NE + 255) / 256, 256, 0, stream>>>(ei, ea, rowPtr, cursor, csr);

  const unsigned short* hin = bufA;
  unsigned short* hout = bufB;
  for (int l = 0; l < LAYERS; ++l){
    hipMemsetAsync(colst, 0, (size_t)NREP * 2 * SD * 4, stream);
    k_fused<<<NN / 64, 256, 0, stream>>>(hin, Wt + (size_t)l * 320 * SD, st,
        rowPtr, deg, csr, e1 + l * 5, e2 + l * 3, bb + l * EMB,
        hout, colst, (l >= 1) ? 1 : 0);
    k_stfin<<<1, SD, 0, stream>>>(colst, gam + l * EMB, bet + l * EMB, st);
    const unsigned short* t = hin; hin = hout; hout = (unsigned short*)t;
  }
  // after 5 layers: hin == bufB (final H), hout == bufA (free -> hg)

  k_pool<<<NG, 320, 0, stream>>>(hin, st, bat, hg);
  k_head1<<<NG, 256, 0, stream>>>(hg, fW, fb, out);
  k_head2<<<NG, 256, 0, stream>>>(out, oW1, ob1, oW2, ob2, out + (size_t)NG * FEAT);
}

// Round 11
// 2416.342 us; speedup vs baseline: 2.9541x; 2.9541x over previous
//
#include <hip/hip_runtime.h>

// Problem constants (match reference)
#define NN   200000   // nodes
#define NE   400000   // edges (without self loops)
#define NG   4096     // graphs
#define EMB  300
#define SD   304      // storage stride in bf16 elems (16B-aligned; 38 slots of 8)
#define SLOTS 38      // 16B slots per stored row
#define NROW 200064   // padded rows (for buffer sizing only)
#define FEAT 256
#define LAYERS 5
#define NREP 16       // stats atomic replicas

typedef __attribute__((ext_vector_type(8))) short short8;   // 8 x bf16 (4 VGPR)
typedef __attribute__((ext_vector_type(4))) float f32x4;

__device__ __forceinline__ float bf2f(unsigned short u){
  union { unsigned int i; float f; } v; v.i = ((unsigned int)u) << 16; return v.f;
}
__device__ __forceinline__ unsigned short f2bf(float f){
  union { float f; unsigned int i; } v; v.f = f;
  return (unsigned short)((v.i + 0x7fffu + ((v.i >> 16) & 1u)) >> 16);
}

// ---------------------------------------------------------------- Wt build
// Wt[l][j][k] = bf16(W[l][k][j]), padded to [320][304] per layer (zeros outside 300x300)
__global__ void k_wt(const float* __restrict__ W, unsigned short* __restrict__ Wt){
  int idx = blockIdx.x * 256 + threadIdx.x;            // 5*320*304 = 486400 items
  if (idx >= LAYERS * 320 * SD) return;
  int l = idx / (320 * SD);
  int rem = idx - l * 320 * SD;
  int j = rem / SD, k = rem - (rem / SD) * SD;
  unsigned short v = 0;
  if (j < EMB && k < EMB) v = f2bf(W[l * EMB * EMB + k * EMB + j]);
  Wt[idx] = v;
}

// ---------------------------------------------------------------- embedding
__global__ __launch_bounds__(256) void k_embed(const int* __restrict__ x,
    const float* __restrict__ emb1, const float* __restrict__ emb2,
    unsigned short* __restrict__ H){
  __shared__ float e1s[900], e2s[900];                 // x values are in [0,3)
  int tid = threadIdx.x;
  for (int k = tid; k < 900; k += 256){ e1s[k] = emb1[k]; e2s[k] = emb2[k]; }
  __syncthreads();
  int t = blockIdx.x * 256 + tid;                      // one 16B slot per thread
  int i = t / SLOTS, c = t - (t / SLOTS) * SLOTS;
  if (i >= NN) return;
  int x0 = x[2 * i], x1 = x[2 * i + 1];
  int cb = c * 8;
  unsigned short o[8];
#pragma unroll
  for (int e = 0; e < 8; ++e){
    int col = cb + e; float v = 0.f;
    if (col < EMB) v = e1s[x0 * EMB + col] + e2s[x1 * EMB + col];
    o[e] = f2bf(v);
  }
  *reinterpret_cast<uint4*>(H + (size_t)i * SD + cb) = *reinterpret_cast<uint4*>(o);
}

// ---------------------------------------------------------------- CSR build
__global__ void k_deg(const int* __restrict__ ei, int* __restrict__ deg){
  int e = blockIdx.x * 256 + threadIdx.x;
  if (e < NE) atomicAdd(&deg[ei[NE + e]], 1);
}
__global__ void k_scan1(const int* __restrict__ deg, int* __restrict__ incl, int* __restrict__ bsum){
  __shared__ int sm[256];
  int t = threadIdx.x; int i = blockIdx.x * 256 + t;
  int v = (i < NN) ? deg[i] : 0; sm[t] = v;
  for (int o = 1; o < 256; o <<= 1){
    __syncthreads(); int xx = (t >= o) ? sm[t - o] : 0;
    __syncthreads(); sm[t] += xx;
  }
  __syncthreads();
  if (i < NN) incl[i] = sm[t];
  if (t == 255) bsum[blockIdx.x] = sm[255];
}
__global__ void k_scan2(const int* __restrict__ bsum, int* __restrict__ bincl){
  __shared__ int sm[1024];
  int t = threadIdx.x;
  int v = (t < 782) ? bsum[t] : 0; sm[t] = v;
  for (int o = 1; o < 1024; o <<= 1){
    __syncthreads(); int xx = (t >= o) ? sm[t - o] : 0;
    __syncthreads(); sm[t] += xx;
  }
  __syncthreads();
  bincl[t] = sm[t];
}
__global__ void k_scan3(const int* __restrict__ incl, const int* __restrict__ deg,
    const int* __restrict__ bincl, int* __restrict__ rowPtr){
  int i = blockIdx.x * 256 + threadIdx.x;
  if (i < NN) rowPtr[i] = incl[i] - deg[i] + (blockIdx.x ? bincl[blockIdx.x - 1] : 0);
}
__global__ void k_fill(const int* __restrict__ ei, const int* __restrict__ ea,
    const int* __restrict__ rowPtr, int* __restrict__ cursor, int* __restrict__ csr){
  int e = blockIdx.x * 256 + threadIdx.x;
  if (e >= NE) return;
  int dst = ei[NE + e], src = ei[e];
  int code = ea[2 * e] * 3 + ea[2 * e + 1];      // ea0,ea1 in 0..2
  int pos = atomicAdd(&cursor[dst], 1);
  csr[rowPtr[dst] + pos] = src | (code << 20);   // src fits 18 bits
}

// ---------------------------------------------------------------- FUSED layer
// Gather phase: 8 threads/row (accv = 40 f32), 32 rows/pass, 2 passes; rows
// written bf16 into XOR-swizzled LDS A-tile. MFMA phase: read A-fragments from
// LDS, stage B-tile into the SAME LDS buffer, MFMA, epilogue+stats+write.
// Register peak ~135 -> 3 waves/SIMD; LDS ~43.7KB -> 3 blocks/CU.
__global__ __launch_bounds__(256, 3) void k_fused(
    const unsigned short* __restrict__ Hin, const unsigned short* __restrict__ Wt,
    const float2* __restrict__ st, const int* __restrict__ rowPtr,
    const int* __restrict__ deg, const int* __restrict__ csr,
    const float* __restrict__ e1l, const float* __restrict__ e2l,
    const float* __restrict__ bl, unsigned short* __restrict__ Hout,
    float* __restrict__ cs, int relu){
  __shared__ unsigned short tLds[64 * 320];   // 40KB: A tile -> B tile -> out tile
  __shared__ float2 stl[SD];
  __shared__ float eetab[9];
  __shared__ float eeself_s;
  __shared__ float cvl[64];
  int tid = threadIdx.x, lane = tid & 63, wave = tid >> 6;
  for (int j = tid; j < SD; j += 256) stl[j] = st[j];
  if (tid < 9) eetab[tid] = e1l[tid / 3] + e2l[tid % 3];
  if (tid == 9) eeself_s = e1l[4] + e2l[0];
  __syncthreads();
  int r0 = blockIdx.x * 64;                    // grid = NN/64 = 3125 exactly
  int g = tid & 7;

  // ---- gather phase: 2 passes of 32 rows ----
#pragma unroll 1
  for (int pass = 0; pass < 2; ++pass){
    int rloc = pass * 32 + (tid >> 3);
    int row = r0 + rloc;
    float accv[5][8];
#pragma unroll
    for (int q = 0; q < 5; ++q)
#pragma unroll
      for (int e = 0; e < 8; ++e) accv[q][e] = 0.f;

    uint4 sA[5], sB[5];
    auto issueA = [&](int src){
      const unsigned short* p = Hin + (size_t)src * SD;
#pragma unroll
      for (int q = 0; q < 5; ++q){
        int ch = q * 8 + g;
        if (ch < SLOTS) sA[q] = *reinterpret_cast<const uint4*>(p + ch * 8);
      }
    };
    auto issueB = [&](int src){
      const unsigned short* p = Hin + (size_t)src * SD;
#pragma unroll
      for (int q = 0; q < 5; ++q){
        int ch = q * 8 + g;
        if (ch < SLOTS) sB[q] = *reinterpret_cast<const uint4*>(p + ch * 8);
      }
    };
    auto consume = [&](const uint4 (&s)[5]){
#pragma unroll
      for (int q = 0; q < 5; ++q){
        int ch = q * 8 + g;
        if (ch < SLOTS){
          unsigned int w[4] = {s[q].x, s[q].y, s[q].z, s[q].w};
          int cb = ch * 8;
#pragma unroll
          for (int e = 0; e < 8; ++e){
            unsigned short u = (e & 1) ? (unsigned short)(w[e >> 1] >> 16)
                                       : (unsigned short)(w[e >> 1] & 0xffff);
            float2 sv = stl[cb + e];
            float xv = sv.x * bf2f(u) + sv.y;
            if (relu) xv = fmaxf(xv, 0.f);
            accv[q][e] += xv;
          }
        }
      }
    };

    float csum = eeself_s;
    int st0 = rowPtr[row], cnt = deg[row];
    issueA(row);                               // self row in flight
    int e = 0;
    for (; e + 1 < cnt; e += 2){               // double-buffered edge pipeline
      int p0 = csr[st0 + e];
      csum += eetab[p0 >> 20];
      issueB(p0 & 0xFFFFF);
      consume(sA);
      int p1 = csr[st0 + e + 1];
      csum += eetab[p1 >> 20];
      issueA(p1 & 0xFFFFF);
      consume(sB);
    }
    if (e < cnt){
      int p0 = csr[st0 + e];
      csum += eetab[p0 >> 20];
      issueB(p0 & 0xFFFFF);
      consume(sA);
      consume(sB);
    } else {
      consume(sA);
    }
    if (g == 0) cvl[rloc] = csum;

    // write bf16 row slice into swizzled LDS A-tile (chunk ch -> ch^(rloc&7))
#pragma unroll
    for (int q = 0; q < 5; ++q){
      int ch = q * 8 + g;
      int p = ch ^ (rloc & 7);
      unsigned short o[8];
#pragma unroll
      for (int e2_ = 0; e2_ < 8; ++e2_)
        o[e2_] = (ch < SLOTS) ? f2bf(accv[q][e2_]) : (unsigned short)0;
      *reinterpret_cast<uint4*>(&tLds[rloc * 320 + p * 8]) = *reinterpret_cast<uint4*>(o);
    }
  }
  __syncthreads();

  // ---- read MFMA A-fragments from swizzled LDS A-tile ----
  int kg = lane >> 4;
  int rr = wave * 16 + (lane & 15);
  short8 afr[10];
#pragma unroll
  for (int m = 0; m < 10; ++m){
    int c = m * 4 + kg;
    int p = c ^ (rr & 7);
    afr[m] = *reinterpret_cast<const short8*>(&tLds[rr * 320 + p * 8]);
  }

  // ---- MFMA phase (B staged into same LDS; barrier at loop top orders it) ----
  f32x4 acc[20];
#pragma unroll
  for (int a = 0; a < 20; ++a) acc[a] = (f32x4){0.f, 0.f, 0.f, 0.f};
#pragma unroll
  for (int jt = 0; jt < 5; ++jt){
    __syncthreads();
#pragma unroll
    for (int it = 0; it < 10; ++it){
      int s = it * 256 + tid;
      int jl = s / 40, cc = s - (s / 40) * 40;
      int srcC = cc ^ (jl & 7);
      uint4 v = make_uint4(0u, 0u, 0u, 0u);
      if (srcC < SLOTS)
        v = *reinterpret_cast<const uint4*>(Wt + ((size_t)(jt * 64 + jl) * SD + srcC * 8));
      *reinterpret_cast<uint4*>(&tLds[jl * 320 + cc * 8]) = v;
    }
    __syncthreads();
#pragma unroll
    for (int kc = 0; kc < 10; ++kc){
#pragma unroll
      for (int fl = 0; fl < 4; ++fl){
        int jl = fl * 16 + (lane & 15);
        int cw = kc * 4 + (lane >> 4);
        int cs_ = cw ^ (jl & 7);
        short8 bfr = *reinterpret_cast<const short8*>(&tLds[jl * 320 + cs_ * 8]);
        acc[jt * 4 + fl] = __builtin_amdgcn_mfma_f32_16x16x32_bf16(afr[kc], bfr, acc[jt * 4 + fl], 0, 0, 0);
      }
    }
  }
  __syncthreads();
  // ---- epilogue: + cvl + bias, stage bf16 tile into LDS (reuse tLds)
  unsigned short* oLds = tLds;
  {
    int rb = wave * 16 + (lane >> 4) * 4;
#pragma unroll
    for (int r = 0; r < 4; ++r){
      int lrow = rb + r;
      float cv = cvl[lrow];
#pragma unroll
      for (int a = 0; a < 20; ++a){
        int col = (a >> 2) * 64 + (a & 3) * 16 + (lane & 15);
        if (col < SD){
          float bv = (col < EMB) ? bl[col] : 0.f;
          oLds[lrow * SD + col] = f2bf(acc[a][r] + cv + bv);
        }
      }
    }
  }
  __syncthreads();
  // ---- fused BN stats: column sum/sumsq over 64 rows (NREP atomic replicas)
  {
    float* csr_ = cs + (size_t)(blockIdx.x & (NREP - 1)) * 2 * SD;
    for (int c = tid; c < EMB; c += 256){
      float s = 0.f, s2 = 0.f;
#pragma unroll 4
      for (int r = 0; r < 64; ++r){
        float v = bf2f(oLds[r * SD + c]);
        s += v; s2 += v * v;
      }
      atomicAdd(&csr_[c], s); atomicAdd(&csr_[SD + c], s2);
    }
  }
  // ---- coalesced contiguous tile write (2432 consecutive 16B slots)
  for (int s = tid; s < 64 * SLOTS; s += 256){
    *reinterpret_cast<uint4*>(Hout + (size_t)r0 * SD + s * 8) =
        *reinterpret_cast<const uint4*>(&tLds[(s / SLOTS) * SD + (s - (s / SLOTS) * SLOTS) * 8]);
  }
}

// ---------------------------------------------------------------- BN finalize
__global__ void k_stfin(const float* __restrict__ cs, const float* __restrict__ gam,
    const float* __restrict__ bet, float2* __restrict__ st){
  int j = threadIdx.x;            // SD threads
  if (j < EMB){
    float sm = 0.f, sq = 0.f;
    for (int r = 0; r < NREP; ++r){
      sm += cs[(size_t)r * 2 * SD + j];
      sq += cs[(size_t)r * 2 * SD + SD + j];
    }
    float mean = sm * (1.f / NN);
    float var = sq * (1.f / NN) - mean * mean;
    float rr = rsqrtf(var + 1e-5f);
    float s = gam[j] * rr;
    st[j] = make_float2(s, bet[j] - mean * s);
  } else if (j < SD) st[j] = make_float2(0.f, 0.f);
}
__global__ void k_stinit(float2* __restrict__ st){
  int j = threadIdx.x; if (j < SD) st[j] = make_float2(1.f, 0.f);
}

// ---------------------------------------------------------------- pool + heads
__global__ void k_pool(const unsigned short* __restrict__ H, const float2* __restrict__ st,
    const int* __restrict__ batch, float* __restrict__ hg){
  int gph = blockIdx.x, j = threadIdx.x;     // 320 threads
  if (j >= SD) return;
  int lo, hi;
  { int a = 0, bn = NN; while (a < bn){ int m = (a + bn) >> 1; if (batch[m] < gph) a = m + 1; else bn = m; } lo = a; }
  { int a = lo, bn = NN; while (a < bn){ int m = (a + bn) >> 1; if (batch[m] < gph + 1) a = m + 1; else bn = m; } hi = a; }
  float acc = 0.f;
  for (int i = lo; i < hi; ++i) acc += bf2f(H[(size_t)i * SD + j]);
  int cnt = hi - lo;
  float2 sv = st[j];
  hg[gph * SD + j] = (sv.x * acc + (float)cnt * sv.y) / (float)max(cnt, 1);
}
__global__ __launch_bounds__(256) void k_head1(const float* __restrict__ hg,
    const float* __restrict__ fW, const float* __restrict__ fb,
    float* __restrict__ out0){
  __shared__ float row[EMB];
  int g = blockIdx.x, t = threadIdx.x;
  for (int j = t; j < EMB; j += 256) row[j] = hg[g * SD + j];
  __syncthreads();
  float acc = fb[t];
  for (int j = 0; j < EMB; ++j) acc += row[j] * fW[j * FEAT + t];
  out0[g * FEAT + t] = acc;
}
__global__ __launch_bounds__(256) void k_head2(const float* __restrict__ hf,
    const float* __restrict__ W1, const float* __restrict__ b1,
    const float* __restrict__ W2, const float* __restrict__ b2,
    float* __restrict__ out1){
  __shared__ float row[FEAT];
  __shared__ float t1[FEAT];
  int g = blockIdx.x, t = threadIdx.x;
  row[t] = hf[g * FEAT + t];
  __syncthreads();
  float acc = b1[t];
  for (int k = 0; k < FEAT; ++k) acc += row[k] * W1[k * FEAT + t];
  t1[t] = fmaxf(acc, 0.f);
  __syncthreads();
  if (t < 128){
    float a2 = b2[t];
    for (int k = 0; k < FEAT; ++k) a2 += t1[k] * W2[k * 128 + t];
    out1[g * 128 + t] = a2;
  }
}

// ---------------------------------------------------------------- launcher
extern "C" void kernel_launch(void* const* d_in, const int* in_sizes, int n_in,
                              void* d_out, int out_size, void* d_ws, size_t ws_size,
                              hipStream_t stream){
  const int* x   = (const int*)d_in[0];
  const int* ei  = (const int*)d_in[1];
  const int* ea  = (const int*)d_in[2];
  const int* bat = (const int*)d_in[3];
  const float* emb1 = (const float*)d_in[4];
  const float* emb2 = (const float*)d_in[5];
  const float* W    = (const float*)d_in[6];
  const float* bb   = (const float*)d_in[7];
  const float* e1   = (const float*)d_in[8];
  const float* e2   = (const float*)d_in[9];
  const float* gam  = (const float*)d_in[10];
  const float* bet  = (const float*)d_in[11];
  const float* fW   = (const float*)d_in[12];
  const float* fb   = (const float*)d_in[13];
  const float* oW1  = (const float*)d_in[14];
  const float* ob1  = (const float*)d_in[15];
  const float* oW2  = (const float*)d_in[16];
  const float* ob2  = (const float*)d_in[17];
  float* out = (float*)d_out;

  // carve workspace (~248 MB total)
  unsigned char* ws = (unsigned char*)d_ws;
  size_t off = 0;
  auto carve = [&](size_t bytes) -> void* {
    off = (off + 255) & ~(size_t)255;
    void* p = ws + off; off += bytes; return p;
  };
  const size_t SZ_H = (size_t)NROW * SD * 2;                       // 121,638,912 B
  unsigned short* bufA = (unsigned short*)carve(SZ_H);
  unsigned short* bufB = (unsigned short*)carve(SZ_H);
  unsigned short* Wt = (unsigned short*)carve((size_t)LAYERS * 320 * SD * 2);
  int* deg     = (int*)carve((size_t)NN * 4);
  int* rowPtr  = (int*)carve((size_t)NN * 4);
  int* csr     = (int*)carve((size_t)NE * 4);
  int* bsum    = (int*)carve(1024 * 4);
  int* bincl   = (int*)carve(1024 * 4);
  float* colst = (float*)carve((size_t)NREP * 2 * SD * 4);
  float2* st   = (float2*)carve(SD * 8);
  size_t needed = off;
  if (ws_size < needed) return;   // diagnostic: finite absmax-fail => ws too small

  // dead-time aliases:
  //   incl/cursor live only during CSR build (before bufB's first write, layer 0);
  //   hg lives only after bufA's last read (layer-4 k_fused reads bufA, writes bufB).
  int* incl    = (int*)bufB;
  int* cursor  = (int*)((unsigned char*)bufB + (size_t)NN * 4);
  float* hg    = (float*)bufA;

  hipMemsetAsync(deg, 0, (size_t)NN * 4, stream);
  hipMemsetAsync(cursor, 0, (size_t)NN * 4, stream);

  k_wt<<<(LAYERS * 320 * SD + 255) / 256, 256, 0, stream>>>(W, Wt);
  k_embed<<<(NN * SLOTS + 255) / 256, 256, 0, stream>>>(x, emb1, emb2, bufA);
  k_stinit<<<1, SD, 0, stream>>>(st);
  k_deg<<<(NE + 255) / 256, 256, 0, stream>>>(ei, deg);
  k_scan1<<<782, 256, 0, stream>>>(deg, incl, bsum);
  k_scan2<<<1, 1024, 0, stream>>>(bsum, bincl);
  k_scan3<<<782, 256, 0, stream>>>(incl, deg, bincl, rowPtr);
  k_fill<<<(NE + 255) / 256, 256, 0, stream>>>(ei, ea, rowPtr, cursor, csr);

  const unsigned short* hin = bufA;
  unsigned short* hout = bufB;
  for (int l = 0; l < LAYERS; ++l){
    hipMemsetAsync(colst, 0, (size_t)NREP * 2 * SD * 4, stream);
    k_fused<<<NN / 64, 256, 0, stream>>>(hin, Wt + (size_t)l * 320 * SD, st,
        rowPtr, deg, csr, e1 + l * 5, e2 + l * 3, bb + l * EMB,
        hout, colst, (l >= 1) ? 1 : 0);
    k_stfin<<<1, SD, 0, stream>>>(colst, gam + l * EMB, bet + l * EMB, st);
    const unsigned short* t = hin; hin = hout; hout = (unsigned short*)t;
  }
  // after 5 layers: hin == bufB (final H), hout == bufA (free -> hg)

  k_pool<<<NG, 320, 0, stream>>>(hin, st, bat, hg);
  k_head1<<<NG, 256, 0, stream>>>(hg, fW, fb, out);
  k_head2<<<NG, 256, 0, stream>>>(out, oW1, ob1, oW2, ob2, out + (size_t)NG * FEAT);
}